// Round 6
// baseline (203.922 us; speedup 1.0000x reference)
//
#include <hip/hip_runtime.h>

#define WIN 33
#define WIDTH 128
#define MPTS 64
#define NN 2048
#define MM 2048
#define DD 64
#define NQ 2080   // N + 2L

typedef __bf16 bf16x8 __attribute__((ext_vector_type(8)));
typedef float f32x4 __attribute__((ext_vector_type(4)));

__device__ __forceinline__ unsigned short f2bf(float x) {
  union { float f; unsigned int u; } v; v.f = x;
  unsigned int r = v.u + 0x7FFFu + ((v.u >> 16) & 1u);  // RNE
  return (unsigned short)(r >> 16);
}
__device__ __forceinline__ float sigf(float x) { return 1.0f / (1.0f + __expf(-x)); }

// async global->LDS, 16B per lane; lds dest must be wave-uniform base
__device__ __forceinline__ void gload16(const void* g, void* l) {
  __builtin_amdgcn_global_load_lds(
      (const __attribute__((address_space(1))) unsigned int*)g,
      (__attribute__((address_space(3))) unsigned int*)l, 16, 0, 0);
}

// ------------- xi[M][NQ] f32  ->  xiT[NQ][M] bf16 (transpose + convert) ----
__global__ __launch_bounds__(256) void k_transpose(const float* __restrict__ xi,
                                                   unsigned short* __restrict__ xiT) {
  __shared__ float ts[64 * 37];
  int qb = blockIdx.x * 32;                // 65 tiles over NQ=2080
  int mb = blockIdx.y * 64;                // 32 tiles over M=2048
#pragma unroll
  for (int c = threadIdx.x; c < 512; c += 256) {   // 64 rows x 8 float4
    int row = c >> 3, c8 = c & 7;
    float4 v = *(const float4*)&xi[(size_t)(mb + row) * NQ + qb + (c8 << 2)];
    ts[row * 37 + (c8 << 2) + 0] = v.x;
    ts[row * 37 + (c8 << 2) + 1] = v.y;
    ts[row * 37 + (c8 << 2) + 2] = v.z;
    ts[row * 37 + (c8 << 2) + 3] = v.w;
  }
  __syncthreads();
#pragma unroll
  for (int c = threadIdx.x; c < 512; c += 256) {   // 32 q-rows x 16 m-quads
    int r = c >> 4, mq = c & 15;
    ushort4 h;
    h.x = f2bf(ts[(mq * 4 + 0) * 37 + r]);
    h.y = f2bf(ts[(mq * 4 + 1) * 37 + r]);
    h.z = f2bf(ts[(mq * 4 + 2) * 37 + r]);
    h.w = f2bf(ts[(mq * 4 + 3) * 37 + r]);
    *(ushort4*)&xiT[(size_t)(qb + r) * MM + mb + (mq << 2)] = h;
  }
}

// ------------- fused: per-(j, m-tile) MLP recompute + final-layer GEMM -----
// Gt2[j][p][m] = sig(wf[m][j]·u1_j[:,p] + bfin);  u1_j recomputed per block.
__global__ __launch_bounds__(256) void k_gt(const float* __restrict__ u,
                                            const float* __restrict__ w0,
                                            const float* __restrict__ b0,
                                            const float* __restrict__ w,
                                            const float* __restrict__ bias,
                                            const float* __restrict__ wf,
                                            const float* __restrict__ bfin,
                                            unsigned short* __restrict__ Gt2) {
  constexpr int WS = 72;
  constexpr int AS = 136;
  __shared__ unsigned short ws[128 * WS];   // weights; reused as wf tile (64x136)
  __shared__ unsigned short actA[64 * AS];
  __shared__ unsigned short actB[64 * AS];
  __shared__ float biass[128];
  int bid = blockIdx.x;                     // 33*32
  int j = bid >> 5;
  int m0 = (bid & 31) << 6;
  int tid = threadIdx.x;
  int wv = tid >> 6, lane = tid & 63, l15 = lane & 15, l4 = lane >> 4;

  // stage u -> actA[p][d], w0[j] -> ws, b0 -> biass
#pragma unroll
  for (int c = tid; c < 1024; c += 256) {
    int p = c >> 4, d4 = (c & 15) << 2;
    float4 v = *(const float4*)&u[(size_t)p * DD + d4];
    ushort4 h; h.x = f2bf(v.x); h.y = f2bf(v.y); h.z = f2bf(v.z); h.w = f2bf(v.w);
    *(ushort4*)&actA[p * AS + d4] = h;
  }
#pragma unroll
  for (int c = tid; c < 2048; c += 256) {
    int k = c >> 4, d4 = (c & 15) << 2;
    float4 v = *(const float4*)&w0[((size_t)j * 128 + k) * DD + d4];
    ushort4 h; h.x = f2bf(v.x); h.y = f2bf(v.y); h.z = f2bf(v.z); h.w = f2bf(v.w);
    *(ushort4*)&ws[k * WS + d4] = h;
  }
  if (tid < 128) biass[tid] = b0[j * 128 + tid];
  __syncthreads();

  {  // layer 0: K=64, actA -> actB
    f32x4 acc[2][4] = {};
#pragma unroll
    for (int t = 0; t < 2; ++t) {
      int col = (t << 5) + (l4 << 3);
      bf16x8 a[2], b[4];
#pragma unroll
      for (int s = 0; s < 2; ++s)
        a[s] = *(const bf16x8*)&ws[(wv * 32 + s * 16 + l15) * WS + col];
#pragma unroll
      for (int q = 0; q < 4; ++q)
        b[q] = *(const bf16x8*)&actA[(q * 16 + l15) * AS + col];
#pragma unroll
      for (int s = 0; s < 2; ++s)
#pragma unroll
        for (int q = 0; q < 4; ++q)
          acc[s][q] = __builtin_amdgcn_mfma_f32_16x16x32_bf16(a[s], b[q], acc[s][q], 0, 0, 0);
    }
#pragma unroll
    for (int s = 0; s < 2; ++s)
#pragma unroll
      for (int q = 0; q < 4; ++q) {
        int p = q * 16 + l15;
#pragma unroll
        for (int r = 0; r < 4; ++r) {
          int k = wv * 32 + s * 16 + (l4 << 2) + r;
          actB[p * AS + k] = f2bf(sigf(acc[s][q][r] + biass[k]));
        }
      }
  }

  unsigned short* ain = actB;
  unsigned short* aout = actA;
#pragma unroll
  for (int i = 0; i < 2; ++i) {             // hidden layers, K=128 in 2 halves
    f32x4 acc[2][4] = {};
    const float* wbase = w + ((size_t)i * WIN + j) * 128 * 128;
#pragma unroll
    for (int h = 0; h < 2; ++h) {
      __syncthreads();
#pragma unroll
      for (int c = tid; c < 2048; c += 256) {
        int k = c >> 4, d4 = (c & 15) << 2;
        float4 v = *(const float4*)&wbase[(size_t)k * 128 + h * 64 + d4];
        ushort4 hh; hh.x = f2bf(v.x); hh.y = f2bf(v.y); hh.z = f2bf(v.z); hh.w = f2bf(v.w);
        *(ushort4*)&ws[k * WS + d4] = hh;
      }
      if (h == 0 && tid < 128) biass[tid] = bias[((size_t)i * WIN + j) * 128 + tid];
      __syncthreads();
#pragma unroll
      for (int t = 0; t < 2; ++t) {
        int col = (t << 5) + (l4 << 3);
        bf16x8 a[2], b[4];
#pragma unroll
        for (int s = 0; s < 2; ++s)
          a[s] = *(const bf16x8*)&ws[(wv * 32 + s * 16 + l15) * WS + col];
#pragma unroll
        for (int q = 0; q < 4; ++q)
          b[q] = *(const bf16x8*)&ain[(q * 16 + l15) * AS + h * 64 + col];
#pragma unroll
        for (int s = 0; s < 2; ++s)
#pragma unroll
          for (int q = 0; q < 4; ++q)
            acc[s][q] = __builtin_amdgcn_mfma_f32_16x16x32_bf16(a[s], b[q], acc[s][q], 0, 0, 0);
      }
    }
#pragma unroll
    for (int s = 0; s < 2; ++s)
#pragma unroll
      for (int q = 0; q < 4; ++q) {
        int p = q * 16 + l15;
#pragma unroll
        for (int r = 0; r < 4; ++r) {
          int k = wv * 32 + s * 16 + (l4 << 2) + r;
          aout[p * AS + k] = f2bf(sigf(acc[s][q][r] + biass[k]));
        }
      }
    unsigned short* t2 = ain; ain = aout; aout = t2;
  }
  // ain = u1_j in [p][k] layout (stride AS). Final GEMM: C[64m x 64p].
  __syncthreads();                          // ws reads & ain writes complete
  unsigned short* wfs = ws;                 // reuse as 64 x 136 tile
#pragma unroll
  for (int c = tid; c < 64 * 32; c += 256) {
    int row = c >> 5, f4 = c & 31;
    float4 v = *(const float4*)(wf + ((size_t)(m0 + row) * WIN + j) * WIDTH + (f4 << 2));
    ushort4 h;
    h.x = f2bf(v.x); h.y = f2bf(v.y); h.z = f2bf(v.z); h.w = f2bf(v.w);
    *(ushort4*)(&wfs[row * AS + (f4 << 2)]) = h;
  }
  __syncthreads();
  f32x4 facc[4] = {};
#pragma unroll
  for (int t = 0; t < 4; ++t) {
    int col = (t << 5) + (l4 << 3);
    bf16x8 a = *(const bf16x8*)(&wfs[(wv * 16 + l15) * AS + col]);
#pragma unroll
    for (int q = 0; q < 4; ++q) {
      bf16x8 bb = *(const bf16x8*)(&ain[(q * 16 + l15) * AS + col]);
      facc[q] = __builtin_amdgcn_mfma_f32_16x16x32_bf16(a, bb, facc[q], 0, 0, 0);
    }
  }
#pragma unroll
  for (int q = 0; q < 4; ++q) {
    int mr = m0 + wv * 16 + (l4 << 2);
    int p = q * 16 + l15;
    float z0 = facc[q][0] + bfin[(size_t)(mr + 0) * WIN + j];
    float z1 = facc[q][1] + bfin[(size_t)(mr + 1) * WIN + j];
    float z2 = facc[q][2] + bfin[(size_t)(mr + 2) * WIN + j];
    float z3 = facc[q][3] + bfin[(size_t)(mr + 3) * WIN + j];
    ushort4 st;
    st.x = f2bf(sigf(z0)); st.y = f2bf(sigf(z1));
    st.z = f2bf(sigf(z2)); st.w = f2bf(sigf(z3));
    *(ushort4*)(&Gt2[(size_t)(j * MPTS + p) * MM + mr]) = st;
  }
}

// ------------- phase C: out[n,p] += sum_{j,m} xiT[n+j,m] * Gt2[j,p,m] ------
// grid 1024 = 16 nt(128) x 64 mp(32); XCD = mp%8 -> Gt2 slice L2-resident.
// 128 thr (2 waves), wave-tile 64n x 64p. A resident (10 KB). B per-j 4 KB,
// triple-buffered, global_load_lds w=16, distance-2 prefetch, raw s_barrier
// + manual vmcnt(2) (never full drain in steady state).
__global__ __launch_bounds__(128, 2) void k_conv(const unsigned short* __restrict__ xiT,
                                                 const unsigned short* __restrict__ Gt2,
                                                 float* __restrict__ out) {
  __shared__ unsigned short As[160 * 32];   // rows n0..n0+159, 32 m (64 B rows)
  __shared__ unsigned short Bs[3 * 64 * 32];// 3 bufs of 64p x 32m
  int bid = blockIdx.x;
  int mp = bid & 63;                        // m-chunk (XCD = mp%8)
  int n0 = (bid >> 6) << 7;                 // 16 n-tiles of 128
  int m0 = mp << 5;
  int tid = threadIdx.x;
  int wv = tid >> 6, lane = tid & 63, l15 = lane & 15, l4 = lane >> 4;
  int sp = lane >> 2, smq = lane & 3;       // B staging coords

  // A stage (once): 640 uint4, conflict-free ds_write
  for (int c = tid; c < 640; c += 128) {
    int row = c >> 2, g = c & 3;
    *(uint4*)(&As[row * 32 + (g << 3)]) =
        *(const uint4*)(xiT + (size_t)(n0 + row) * MM + m0 + (g << 3));
  }
  // B issue for batch j into buf j%3: 2 global_load_lds per lane (r=0,1)
#define ISSUE_B(J)                                                              \
  {                                                                             \
    int _b = (J) % 3;                                                           \
    _Pragma("unroll")                                                           \
    for (int r = 0; r < 2; ++r) {                                               \
      const unsigned short* g =                                                 \
          Gt2 + ((size_t)((J) * 64 + wv * 32 + r * 16 + sp)) * MM + m0 + (smq << 3); \
      gload16(g, &Bs[_b * 2048 + wv * 1024 + r * 512]);                         \
    }                                                                           \
  }
  ISSUE_B(0);
  ISSUE_B(1);
  __syncthreads();                          // full drain once: A + j0/j1 visible

  f32x4 acc[4][4] = {};
#define COMPUTE(J)                                                              \
  {                                                                             \
    unsigned short* Bb = &Bs[((J) % 3) * 2048];                                 \
    bf16x8 a[4], b[4];                                                          \
    _Pragma("unroll")                                                           \
    for (int s = 0; s < 4; ++s)                                                 \
      a[s] = *(const bf16x8*)(&As[(wv * 64 + s * 16 + l15 + (J)) * 32 + (l4 << 3)]); \
    _Pragma("unroll")                                                           \
    for (int q = 0; q < 4; ++q)                                                 \
      b[q] = *(const bf16x8*)(&Bb[(q * 16 + l15) * 32 + (l4 << 3)]);            \
    _Pragma("unroll")                                                           \
    for (int s = 0; s < 4; ++s)                                                 \
      _Pragma("unroll")                                                         \
      for (int q = 0; q < 4; ++q)                                               \
        acc[s][q] = __builtin_amdgcn_mfma_f32_16x16x32_bf16(a[s], b[q], acc[s][q], 0, 0, 0); \
  }

  for (int j = 0; j < 32; ++j) {
    if (j > 0) {
      __builtin_amdgcn_s_waitcnt(0xF72);    // vmcnt(2): batch j landed
      __builtin_amdgcn_s_barrier();         // raw barrier, no full drain
    }
    if (j + 2 < 33) ISSUE_B(j + 2);
    COMPUTE(j);
  }
  __builtin_amdgcn_s_waitcnt(0xF70);        // vmcnt(0): last batch
  __builtin_amdgcn_s_barrier();
  COMPUTE(32);

#pragma unroll
  for (int s = 0; s < 4; ++s)
#pragma unroll
    for (int q = 0; q < 4; ++q) {
      int nr = n0 + wv * 64 + s * 16 + (l4 << 2);
      int p = q * 16 + l15;
#pragma unroll
      for (int i = 0; i < 4; ++i)
        atomicAdd(&out[(size_t)(nr + i) * MPTS + p], acc[s][q][i]);
    }
#undef ISSUE_B
#undef COMPUTE
}

extern "C" void kernel_launch(void* const* d_in, const int* in_sizes, int n_in,
                              void* d_out, int out_size, void* d_ws, size_t ws_size,
                              hipStream_t stream) {
  const float* u    = (const float*)d_in[0];  // [64,64]
  const float* w0   = (const float*)d_in[1];  // [33,128,64]
  const float* b0   = (const float*)d_in[2];  // [33,128,1]
  const float* w    = (const float*)d_in[3];  // [2,33,128,128]
  const float* bias = (const float*)d_in[4];  // [2,33,128,1]
  const float* wf   = (const float*)d_in[5];  // [2048,33,128]
  const float* bfin = (const float*)d_in[6];  // [2048,33,1]
  const float* xi   = (const float*)d_in[7];  // [2048,2080]
  float* out = (float*)d_out;                 // [2048,64]
  char* ws = (char*)d_ws;
  unsigned short* xiT = (unsigned short*)(ws);            // 8,519,680 B
  unsigned short* Gt2 = (unsigned short*)(ws + 8519680);  // 8,650,752 B

  hipMemsetAsync(out, 0, (size_t)out_size * sizeof(float), stream);
  k_transpose<<<dim3(65, 32), 256, 0, stream>>>(xi, xiT);
  k_gt<<<33 * 32, 256, 0, stream>>>(u, w0, b0, w, bias, wf, bfin, Gt2);
  k_conv<<<1024, 128, 0, stream>>>(xiT, Gt2, out);
}